// Round 8
// baseline (1912.067 us; speedup 1.0000x reference)
//
#include <hip/hip_runtime.h>
#include <hip/hip_bf16.h>
#include <stdint.h>

#define TT 1024
#define BBATCH 256
#define DD 256
#define HH 256
#define G4 1024   // 4*H

typedef float f32x4 __attribute__((ext_vector_type(4)));
typedef short bf16x8 __attribute__((ext_vector_type(8)));
typedef int   i32x4  __attribute__((ext_vector_type(4)));
typedef unsigned long long u64;

__device__ __forceinline__ float bf2f(unsigned int u) {
  union { unsigned int i; float f; } v; v.i = u << 16; return v.f;
}
__device__ __forceinline__ unsigned short f2bf(float f) {
  union { float f; unsigned int i; } v; v.f = f;
  unsigned int r = v.i + 0x7FFFu + ((v.i >> 16) & 1u);
  return (unsigned short)(r >> 16);
}
__device__ __forceinline__ bf16x8 pack8(const float4& u, const float4& v) {
  bf16x8 r;
  r[0] = (short)f2bf(u.x); r[1] = (short)f2bf(u.y); r[2] = (short)f2bf(u.z); r[3] = (short)f2bf(u.w);
  r[4] = (short)f2bf(v.x); r[5] = (short)f2bf(v.y); r[6] = (short)f2bf(v.z); r[7] = (short)f2bf(v.w);
  return r;
}

// ---------------- prep kernels ----------------

// W_ih fp32 [1024 g][256 k] -> bf16 frag-packed for the worker's B staging:
// g = sec*256+n, n = wc*32 + nt*16 + lr; k: s=k>>5, hi=(k>>3)&3, el=k&7.
// elem idx = s*32768 + ((wc*8 + sec*2+nt)*64 + (lr|hi<<4))*8 + el
// -> per k-slice s: one contiguous 64KB image; per wave frag read = lane*16B contiguous.
__global__ void prep_wih(const float* __restrict__ wih, unsigned short* __restrict__ out) {
  int g = blockIdx.x;          // 0..1023
  int lane = threadIdx.x;      // 0..63
  int sec = g >> 8, n = g & 255;
  int wc = n >> 5, nt = (n >> 4) & 1, lr = n & 15;
  int k0 = lane * 4;
  int s = k0 >> 5, hi = (k0 >> 3) & 3, el = k0 & 7;
  size_t us = (size_t)s * 32768
            + (size_t)((wc * 8 + sec * 2 + nt) * 64 + (lr | (hi << 4))) * 8 + el;
#pragma unroll
  for (int j2 = 0; j2 < 4; ++j2) out[us + j2] = f2bf(wih[g * 256 + k0 + j2]);
}

__global__ void prep_wyt(const float* __restrict__ wy, unsigned short* __restrict__ wyt) {
  int k = blockIdx.x;
  int d = threadIdx.x;
  wyt[d * 256 + k] = f2bf(wy[k * 256 + d]);
}

// W_hh fp32 [1024 g][256 k] -> per-row-scaled int8 packed in MFMA B-frag order for the
// 16-wave scan: g = sec*256 + n, n = w*16 + cl. Frag slot [((w*4+sec)*4+kt)*64 + lane].
__global__ void prep_whh(const float* __restrict__ whh, const float* __restrict__ h0,
                         signed char* __restrict__ wq, float* __restrict__ dsc,
                         float* __restrict__ hh0) {
  int g = blockIdx.x;
  int lane = threadIdx.x;
  float v[4];
  float mx = 0.f, acc = 0.f;
#pragma unroll
  for (int j = 0; j < 4; ++j) {
    v[j] = whh[g * 256 + lane * 4 + j];
    mx = fmaxf(mx, fabsf(v[j]));
    acc += v[j] * h0[lane * 4 + j];
  }
#pragma unroll
  for (int off = 32; off; off >>= 1) {
    mx  = fmaxf(mx, __shfl_xor(mx, off));
    acc = acc + __shfl_xor(acc, off);
  }
  mx = fmaxf(mx, 1e-12f);
  if (lane == 0) { dsc[g] = mx / (127.f * 127.f); hh0[g] = acc; }
  int sec = g >> 8, w = (g >> 4) & 15, cl = g & 15;
  float inv = 127.f / mx;
  int k0 = lane * 4;
  int kt = k0 >> 6, hi = (k0 >> 4) & 3, jj = k0 & 15;
  int base = (((w * 4 + sec) * 4 + kt) * 64 + (cl | (hi << 4))) * 16 + jj;
#pragma unroll
  for (int j = 0; j < 4; ++j) {
    int q = (int)rintf(v[j] * inv);
    q = q > 127 ? 127 : (q < -127 ? -127 : q);
    wq[base + j] = (signed char)q;
  }
}

__global__ void zero_sync(int* __restrict__ cnt) {
  if (threadIdx.x < 16) cnt[threadIdx.x] = 0;
}

// ---------------- fused: 64 scan blocks + 192 xw-producer blocks ----------------
// grid 256 x 1024 thr, 1 block/CU, all co-resident. Workers produce xw in 64-step
// chunks (cnt[c] counts finished tiles, target 256); scan gates its prefetches on cnt.
__global__ __launch_bounds__(1024, 4) void fused_scan(
    const float* __restrict__ x, const unsigned short* __restrict__ wb,
    const float* __restrict__ bih, const float* __restrict__ hh0,
    unsigned short* xw, const signed char* __restrict__ wq,
    const float* __restrict__ dsc, const float* __restrict__ c0,
    float* __restrict__ out, int* cnt) {
  __shared__ __align__(16) char lds[131072];
  int tid = threadIdx.x;
  int lane = tid & 63, wv = tid >> 6;

  if (blockIdx.x >= 64) {
    // ================= worker branch: xw tiles (64 trow x 1024 g) =================
    int wid = blockIdx.x - 64;   // 0..191
    int wr = wv >> 3, wc = wv & 7;
    int lr = lane & 15, hi = lane >> 4;
#pragma unroll 1
    for (int tile = wid; tile < 4096; tile += 192) {
      int c = tile >> 8, bb = tile & 255;
      int t0 = c * 64;
      const float* xb = x + ((size_t)bb * TT + t0) * DD;
      f32x4 acc[2][8];   // [mti][sec*2+nt]
#pragma unroll
      for (int m = 0; m < 2; ++m)
#pragma unroll
        for (int j = 0; j < 8; ++j) acc[m][j] = (f32x4){0.f, 0.f, 0.f, 0.f};
      int4 b4[4];
      float4 a4[4];
      bf16x8 afr[2];
      // prologue: slice 0
#pragma unroll
      for (int i = 0; i < 4; ++i)
        b4[i] = *(const int4*)(wb + i * 8192 + tid * 8);
#pragma unroll
      for (int m = 0; m < 2; ++m) {
        const float* ap = xb + (size_t)(wr * 32 + m * 16 + lr) * DD + hi * 8;
        a4[m * 2] = *(const float4*)ap;
        a4[m * 2 + 1] = *(const float4*)(ap + 4);
      }
#pragma unroll
      for (int i = 0; i < 4; ++i)
        *(int4*)(lds + i * 16384 + tid * 16) = b4[i];
      afr[0] = pack8(a4[0], a4[1]);
      afr[1] = pack8(a4[2], a4[3]);
      __syncthreads();
#pragma unroll 1
      for (int s = 0; s < 8; ++s) {
        char* bufc = lds + (s & 1) * 65536;
        if (s < 7) {
#pragma unroll
          for (int i = 0; i < 4; ++i)
            b4[i] = *(const int4*)(wb + (s + 1) * 32768 + i * 8192 + tid * 8);
#pragma unroll
          for (int m = 0; m < 2; ++m) {
            const float* ap = xb + (size_t)(wr * 32 + m * 16 + lr) * DD + (s + 1) * 32 + hi * 8;
            a4[m * 2] = *(const float4*)ap;
            a4[m * 2 + 1] = *(const float4*)(ap + 4);
          }
        }
#pragma unroll
        for (int j = 0; j < 8; ++j) {
          bf16x8 bf = *(const bf16x8*)(bufc + ((wc * 8 + j) * 64 + lane) * 16);
          acc[0][j] = __builtin_amdgcn_mfma_f32_16x16x32_bf16(afr[0], bf, acc[0][j], 0, 0, 0);
          acc[1][j] = __builtin_amdgcn_mfma_f32_16x16x32_bf16(afr[1], bf, acc[1][j], 0, 0, 0);
        }
        if (s < 7) {
          afr[0] = pack8(a4[0], a4[1]);
          afr[1] = pack8(a4[2], a4[3]);
          char* bufn = lds + ((s + 1) & 1) * 65536;
#pragma unroll
          for (int i = 0; i < 4; ++i)
            *(int4*)(bufn + i * 16384 + tid * 16) = b4[i];
        }
        __syncthreads();
      }
      // epilogue: pack 4 secs -> u64 (+bias, +hh0 at trow 0)
#pragma unroll
      for (int nt = 0; nt < 2; ++nt) {
        int n = wc * 32 + nt * 16 + lr;
        float bias[4], h0a[4];
#pragma unroll
        for (int sec = 0; sec < 4; ++sec) { bias[sec] = bih[sec * 256 + n]; h0a[sec] = hh0[sec * 256 + n]; }
#pragma unroll
        for (int m = 0; m < 2; ++m) {
#pragma unroll
          for (int r = 0; r < 4; ++r) {
            int trow = t0 + wr * 32 + m * 16 + hi * 4 + r;
            float e[4];
#pragma unroll
            for (int sec = 0; sec < 4; ++sec)
              e[sec] = acc[m][sec * 2 + nt][r] + bias[sec] + (trow == 0 ? h0a[sec] : 0.f);
            u64 pk = (u64)f2bf(e[0]) | ((u64)f2bf(e[1]) << 16)
                   | ((u64)f2bf(e[2]) << 32) | ((u64)f2bf(e[3]) << 48);
            *(u64*)(xw + ((size_t)trow * BBATCH + bb) * G4 + (size_t)n * 4) = pk;
          }
        }
      }
      __syncthreads();           // all waves' stores drained (vmcnt) before publish
      if (tid == 0) {
        __threadfence();         // L2 writeback so other XCDs see the tile
        atomicAdd(&cnt[c], 1);
      }
    }
    return;
  }

  // ================= scan branch (blocks 0..63) =================
  int lr = lane & 15, q = lane >> 4;
  int b0 = blockIdx.x * 4;
  signed char* hqb = (signed char*)lds;   // 8KB dbuf int8 h A-frags
  int nn = wv * 16 + lr;

  i32x4 wf[4][4];
  {
    const i32x4* wp = (const i32x4*)wq;
#pragma unroll
    for (int sec = 0; sec < 4; ++sec)
#pragma unroll
      for (int kt = 0; kt < 4; ++kt) wf[sec][kt] = wp[((wv * 4 + sec) * 4 + kt) * 64 + lane];
  }
  float dr[4];
#pragma unroll
  for (int sec = 0; sec < 4; ++sec) dr[sec] = dsc[sec * 256 + nn];
  float cr = c0[nn], lh = 0.f;

  *(u64*)(hqb + tid * 8) = 0ull;   // zero both hq buffers

  // gate chunk 0 before prologue prefetch
  if (tid == 0) {
    while (__hip_atomic_load(&cnt[0], __ATOMIC_ACQUIRE, __HIP_MEMORY_SCOPE_AGENT) < 256)
      __builtin_amdgcn_s_sleep(16);
  }
  __syncthreads();   // hq zero + gate visible

  unsigned short* ldb = xw + (size_t)(b0 + q) * G4 + (size_t)nn * 4;
  unsigned short* stb = xw + (size_t)(b0 + q) * G4 + nn;
  u64 xq[4];
#pragma unroll
  for (int s = 0; s < 2; ++s) {
    xq[s] = *(const u64*)ldb;
    ldb += (size_t)BBATCH * G4;
  }

  const int hqr = lane * 16;
  const int hqw = (wv >> 2) * 1024 + (wv & 3) * 256 + q * 64 + lr;
  const i32x4 zero4 = {0, 0, 0, 0};
  int gated = 0;

#define STEP(XC, XL, RB) { \
    XL = *(const u64*)ldb; \
    ldb += (size_t)BBATCH * G4; \
    i32x4 acc[4]; \
    __builtin_amdgcn_s_setprio(1); \
    _Pragma("unroll") \
    for (int kt = 0; kt < 4; ++kt) { \
      i32x4 af = *(const i32x4*)(hqb + (RB) + hqr + kt * 1024); \
      _Pragma("unroll") \
      for (int sec = 0; sec < 4; ++sec) \
        acc[sec] = __builtin_amdgcn_mfma_i32_16x16x64_i8(af, wf[sec][kt], kt == 0 ? zero4 : acc[sec], 0, 0, 0); \
    } \
    __builtin_amdgcn_s_setprio(0); \
    { \
      u64 v = XC; \
      float gi = fmaf(dr[0], (float)acc[0][0], bf2f((unsigned int)(v & 0xffffu))); \
      float gf = fmaf(dr[1], (float)acc[1][0], bf2f((unsigned int)((v >> 16) & 0xffffu))); \
      float gj = fmaf(dr[2], (float)acc[2][0], bf2f((unsigned int)((v >> 32) & 0xffffu))); \
      float go = fmaf(dr[3], (float)acc[3][0], bf2f((unsigned int)(v >> 48))); \
      float iv = __builtin_amdgcn_rcpf(1.f + __expf(-gi)); \
      float fv = __builtin_amdgcn_rcpf(1.f + __expf(-gf)); \
      float ov = __builtin_amdgcn_rcpf(1.f + __expf(-go)); \
      float jv = fmaf(-2.f, __builtin_amdgcn_rcpf(1.f + __expf(2.f * gj)), 1.f); \
      float cn = fmaf(fv, cr, iv * jv); \
      cr = cn; \
      float th = fmaf(-2.f, __builtin_amdgcn_rcpf(1.f + __expf(2.f * cn)), 1.f); \
      float hn = ov * th; \
      lh = hn; \
      hqb[((RB) ^ 4096) + hqw] = (signed char)(int)rintf(hn * 127.f); \
      stb[0] = f2bf(hn); \
    } \
    stb += (size_t)BBATCH * G4; \
    asm volatile("s_waitcnt lgkmcnt(0)" ::: "memory"); \
    __builtin_amdgcn_s_barrier(); \
  }

#pragma unroll 1
  for (int t = 0; t < TT; t += 4) {
    int need = (t + 5) >> 6;
    need = need > 15 ? 15 : need;
    if (need > gated) {
      if (tid == 0) {
        while (__hip_atomic_load(&cnt[need], __ATOMIC_ACQUIRE, __HIP_MEMORY_SCOPE_AGENT) < 256)
          __builtin_amdgcn_s_sleep(16);
      }
      __syncthreads();
      gated = need;
    }
    STEP(xq[0], xq[2], 0)
    STEP(xq[1], xq[3], 4096)
    STEP(xq[2], xq[0], 0)
    STEP(xq[3], xq[1], 4096)
  }
#undef STEP

  const size_t youts = (size_t)BBATCH * TT * DD;
  out[youts + (size_t)(b0 + q) * HH + nn] = lh;
  out[youts + (size_t)BBATCH * HH + (size_t)(b0 + q) * HH + nn] = cr;
}

// ---------------- phase 3: y = hs @ W_y + b_y ----------------
__global__ __launch_bounds__(256, 4) void y_gemm(const unsigned short* __restrict__ hsx,
                                                 const unsigned short* __restrict__ wyt,
                                                 const float* __restrict__ by,
                                                 float* __restrict__ y) {
  __shared__ __align__(16) unsigned short ha[64 * 256];  // 32KB
  int tid = threadIdx.x;
  int mt = blockIdx.x;
  int bb = mt >> 4;
  int t0 = (mt & 15) * 64;
  {
    int row = tid >> 2, q = tid & 3;
    const unsigned short* src = hsx + (size_t)(t0 + row) * (size_t)(BBATCH * 1024) + (size_t)bb * 1024;
#pragma unroll
    for (int i = 0; i < 8; ++i) {
      int u = q + i * 4;
      int4 vv = *(const int4*)(src + u * 8);
      *(int4*)((char*)ha + row * 512 + ((u * 16) ^ ((row & 7) << 4))) = vv;
    }
  }
  __syncthreads();
  int lane = tid & 63, wv = tid >> 6;
  int wr = wv >> 1, wc = wv & 1;
  int lr = lane & 15, hi = lane >> 4;
#pragma unroll 1
  for (int dblk = 0; dblk < 2; ++dblk) {
    f32x4 acc[2][4];
#pragma unroll
    for (int a = 0; a < 2; ++a)
#pragma unroll
      for (int b = 0; b < 4; ++b) acc[a][b] = (f32x4){0.f, 0.f, 0.f, 0.f};
    int dbase = dblk * 128 + wc * 64;
#pragma unroll
    for (int k0 = 0; k0 < 8; ++k0) {
      bf16x8 a[2], b[4];
#pragma unroll
      for (int mti = 0; mti < 2; ++mti) {
        int row = wr * 32 + mti * 16 + lr;
        a[mti] = *(const bf16x8*)((const char*)ha + row * 512 + ((k0 * 64 + hi * 16) ^ ((row & 7) << 4)));
      }
#pragma unroll
      for (int nt = 0; nt < 4; ++nt) {
        b[nt] = *(const bf16x8*)(wyt + (size_t)(dbase + nt * 16 + lr) * 256 + k0 * 32 + hi * 8);
#pragma unroll
        for (int mti = 0; mti < 2; ++mti)
          acc[mti][nt] = __builtin_amdgcn_mfma_f32_16x16x32_bf16(a[mti], b[nt], acc[mti][nt], 0, 0, 0);
      }
    }
#pragma unroll
    for (int mti = 0; mti < 2; ++mti)
#pragma unroll
      for (int nt = 0; nt < 4; ++nt) {
        int d = dbase + nt * 16 + lr;
        float bv = by[d];
#pragma unroll
        for (int r = 0; r < 4; ++r) {
          int trow = t0 + wr * 32 + mti * 16 + hi * 4 + r;
          y[((size_t)bb * TT + trow) * DD + d] = acc[mti][nt][r] + bv;
        }
      }
  }
}

// ---------------- launch ----------------
extern "C" void kernel_launch(void* const* d_in, const int* in_sizes, int n_in,
                              void* d_out, int out_size, void* d_ws, size_t ws_size,
                              hipStream_t stream) {
  const float* x   = (const float*)d_in[0];
  const float* wih = (const float*)d_in[1];
  const float* bih = (const float*)d_in[2];
  const float* whh = (const float*)d_in[3];
  const float* h0  = (const float*)d_in[4];
  const float* c0  = (const float*)d_in[5];
  const float* wy  = (const float*)d_in[6];
  const float* by  = (const float*)d_in[7];
  float* out = (float*)d_out;
  char* ws = (char*)d_ws;

  size_t off = 0;
  unsigned short* xw = (unsigned short*)(ws + off);
  off += (size_t)(TT + 2) * BBATCH * G4 * 2;   // 512MB + 2-row prefetch slack
  unsigned short* wbf = (unsigned short*)(ws + off); off += (size_t)G4 * DD * 2;
  unsigned short* wyt = (unsigned short*)(ws + off); off += (size_t)HH * DD * 2;
  signed char* wq = (signed char*)(ws + off); off += (size_t)G4 * HH;
  float* dsc = (float*)(ws + off); off += G4 * 4;
  float* hh0 = (float*)(ws + off); off += G4 * 4;
  int* cnt = (int*)(ws + off); off += 64;

  hipLaunchKernelGGL(prep_wih, dim3(1024), dim3(64), 0, stream, wih, wbf);
  hipLaunchKernelGGL(prep_wyt, dim3(256), dim3(256), 0, stream, wy, wyt);
  hipLaunchKernelGGL(prep_whh, dim3(1024), dim3(64), 0, stream, whh, h0, wq, dsc, hh0);
  hipLaunchKernelGGL(zero_sync, dim3(1), dim3(64), 0, stream, cnt);
  hipLaunchKernelGGL(fused_scan, dim3(256), dim3(1024), 0, stream,
                     x, wbf, bih, hh0, xw, wq, dsc, c0, out, cnt);
  hipLaunchKernelGGL(y_gemm, dim3(4096), dim3(256), 0, stream, xw, wyt, by, out);
}

// Round 9
// 1663.080 us; speedup vs baseline: 1.1497x; 1.1497x over previous
//
#include <hip/hip_runtime.h>
#include <hip/hip_bf16.h>
#include <stdint.h>

#define TT 1024
#define BBATCH 256
#define DD 256
#define HH 256
#define G4 1024   // 4*H

typedef float f32x4 __attribute__((ext_vector_type(4)));
typedef short bf16x8 __attribute__((ext_vector_type(8)));
typedef int   i32x4  __attribute__((ext_vector_type(4)));
typedef unsigned long long u64;

__device__ __forceinline__ float bf2f(unsigned int u) {
  union { unsigned int i; float f; } v; v.i = u << 16; return v.f;
}
__device__ __forceinline__ unsigned short f2bf(float f) {
  union { float f; unsigned int i; } v; v.f = f;
  unsigned int r = v.i + 0x7FFFu + ((v.i >> 16) & 1u);
  return (unsigned short)(r >> 16);
}
__device__ __forceinline__ bf16x8 pack8(const float4& u, const float4& v) {
  bf16x8 r;
  r[0] = (short)f2bf(u.x); r[1] = (short)f2bf(u.y); r[2] = (short)f2bf(u.z); r[3] = (short)f2bf(u.w);
  r[4] = (short)f2bf(v.x); r[5] = (short)f2bf(v.y); r[6] = (short)f2bf(v.z); r[7] = (short)f2bf(v.w);
  return r;
}

// ---------------- prep kernels ----------------

// W_ih fp32 [1024 g][256 k] -> bf16 frag-packed for the worker's B staging.
__global__ void prep_wih(const float* __restrict__ wih, unsigned short* __restrict__ out) {
  int g = blockIdx.x;          // 0..1023
  int lane = threadIdx.x;      // 0..63
  int sec = g >> 8, n = g & 255;
  int wc = n >> 5, nt = (n >> 4) & 1, lr = n & 15;
  int k0 = lane * 4;
  int s = k0 >> 5, hi = (k0 >> 3) & 3, el = k0 & 7;
  size_t us = (size_t)s * 32768
            + (size_t)((wc * 8 + sec * 2 + nt) * 64 + (lr | (hi << 4))) * 8 + el;
#pragma unroll
  for (int j2 = 0; j2 < 4; ++j2) out[us + j2] = f2bf(wih[g * 256 + k0 + j2]);
}

__global__ void prep_wyt(const float* __restrict__ wy, unsigned short* __restrict__ wyt) {
  int k = blockIdx.x;
  int d = threadIdx.x;
  wyt[d * 256 + k] = f2bf(wy[k * 256 + d]);
}

// W_hh fp32 [1024 g][256 k] -> per-row-scaled int8 packed in MFMA B-frag order for the
// 16-wave scan: g = sec*256 + n, n = w*16 + cl. Frag slot [((w*4+sec)*4+kt)*64 + lane].
__global__ void prep_whh(const float* __restrict__ whh, const float* __restrict__ h0,
                         signed char* __restrict__ wq, float* __restrict__ dsc,
                         float* __restrict__ hh0) {
  int g = blockIdx.x;
  int lane = threadIdx.x;
  float v[4];
  float mx = 0.f, acc = 0.f;
#pragma unroll
  for (int j = 0; j < 4; ++j) {
    v[j] = whh[g * 256 + lane * 4 + j];
    mx = fmaxf(mx, fabsf(v[j]));
    acc += v[j] * h0[lane * 4 + j];
  }
#pragma unroll
  for (int off = 32; off; off >>= 1) {
    mx  = fmaxf(mx, __shfl_xor(mx, off));
    acc = acc + __shfl_xor(acc, off);
  }
  mx = fmaxf(mx, 1e-12f);
  if (lane == 0) { dsc[g] = mx / (127.f * 127.f); hh0[g] = acc; }
  int sec = g >> 8, w = (g >> 4) & 15, cl = g & 15;
  float inv = 127.f / mx;
  int k0 = lane * 4;
  int kt = k0 >> 6, hi = (k0 >> 4) & 3, jj = k0 & 15;
  int base = (((w * 4 + sec) * 4 + kt) * 64 + (cl | (hi << 4))) * 16 + jj;
#pragma unroll
  for (int j = 0; j < 4; ++j) {
    int q = (int)rintf(v[j] * inv);
    q = q > 127 ? 127 : (q < -127 ? -127 : q);
    wq[base + j] = (signed char)q;
  }
}

__global__ void zero_sync(int* __restrict__ cnt) {
  if (threadIdx.x < 16) cnt[threadIdx.x] = 0;
}

// ---------------- fused: 64 scan blocks + 192 xw-producer blocks ----------------
// grid 256 x 1024 thr, 1 block/CU (128KB LDS), all co-resident. Workers produce xw
// in 64-step chunks; scan gates prefetches on cnt[c]==256.
// Sync discipline (the R8 fix): workers release-ONLY fence (wbl2, no inv) once per
// tile; scan polls RELAXED (no cache ops) and issues ONE acquire fence per gate.
__global__ __launch_bounds__(1024, 4) void fused_scan(
    const float* __restrict__ x, const unsigned short* __restrict__ wb,
    const float* __restrict__ bih, const float* __restrict__ hh0,
    unsigned short* xw, const signed char* __restrict__ wq,
    const float* __restrict__ dsc, const float* __restrict__ c0,
    float* __restrict__ out, int* cnt) {
  __shared__ __align__(16) char lds[131072];
  int tid = threadIdx.x;
  int lane = tid & 63, wv = tid >> 6;

  if (blockIdx.x >= 64) {
    // ================= worker branch: xw tiles (64 trow x 1024 g) =================
    int wid = blockIdx.x - 64;   // 0..191
    int wr = wv >> 3, wc = wv & 7;
    int lr = lane & 15, hi = lane >> 4;
#pragma unroll 1
    for (int tile = wid; tile < 4096; tile += 192) {
      int c = tile >> 8, bb = tile & 255;
      int t0 = c * 64;
      const float* xb = x + ((size_t)bb * TT + t0) * DD;
      f32x4 acc[2][8];   // [mti][sec*2+nt]
#pragma unroll
      for (int m = 0; m < 2; ++m)
#pragma unroll
        for (int j = 0; j < 8; ++j) acc[m][j] = (f32x4){0.f, 0.f, 0.f, 0.f};
      int4 b4[4];
      float4 a4[4];
      bf16x8 afr[2];
      // prologue: slice 0
#pragma unroll
      for (int i = 0; i < 4; ++i)
        b4[i] = *(const int4*)(wb + i * 8192 + tid * 8);
#pragma unroll
      for (int m = 0; m < 2; ++m) {
        const float* ap = xb + (size_t)(wr * 32 + m * 16 + lr) * DD + hi * 8;
        a4[m * 2] = *(const float4*)ap;
        a4[m * 2 + 1] = *(const float4*)(ap + 4);
      }
#pragma unroll
      for (int i = 0; i < 4; ++i)
        *(int4*)(lds + i * 16384 + tid * 16) = b4[i];
      afr[0] = pack8(a4[0], a4[1]);
      afr[1] = pack8(a4[2], a4[3]);
      __syncthreads();
#pragma unroll 1
      for (int s = 0; s < 8; ++s) {
        char* bufc = lds + (s & 1) * 65536;
        if (s < 7) {
#pragma unroll
          for (int i = 0; i < 4; ++i)
            b4[i] = *(const int4*)(wb + (s + 1) * 32768 + i * 8192 + tid * 8);
#pragma unroll
          for (int m = 0; m < 2; ++m) {
            const float* ap = xb + (size_t)(wr * 32 + m * 16 + lr) * DD + (s + 1) * 32 + hi * 8;
            a4[m * 2] = *(const float4*)ap;
            a4[m * 2 + 1] = *(const float4*)(ap + 4);
          }
        }
#pragma unroll
        for (int j = 0; j < 8; ++j) {
          bf16x8 bf = *(const bf16x8*)(bufc + ((wc * 8 + j) * 64 + lane) * 16);
          acc[0][j] = __builtin_amdgcn_mfma_f32_16x16x32_bf16(afr[0], bf, acc[0][j], 0, 0, 0);
          acc[1][j] = __builtin_amdgcn_mfma_f32_16x16x32_bf16(afr[1], bf, acc[1][j], 0, 0, 0);
        }
        if (s < 7) {
          afr[0] = pack8(a4[0], a4[1]);
          afr[1] = pack8(a4[2], a4[3]);
          char* bufn = lds + ((s + 1) & 1) * 65536;
#pragma unroll
          for (int i = 0; i < 4; ++i)
            *(int4*)(bufn + i * 16384 + tid * 16) = b4[i];
        }
        __syncthreads();
      }
      // epilogue: pack 4 secs -> u64 (+bias, +hh0 at trow 0)
#pragma unroll
      for (int nt = 0; nt < 2; ++nt) {
        int n = wc * 32 + nt * 16 + lr;
        float bias[4], h0a[4];
#pragma unroll
        for (int sec = 0; sec < 4; ++sec) { bias[sec] = bih[sec * 256 + n]; h0a[sec] = hh0[sec * 256 + n]; }
#pragma unroll
        for (int m = 0; m < 2; ++m) {
#pragma unroll
          for (int r = 0; r < 4; ++r) {
            int trow = t0 + wr * 32 + m * 16 + hi * 4 + r;
            float e[4];
#pragma unroll
            for (int sec = 0; sec < 4; ++sec)
              e[sec] = acc[m][sec * 2 + nt][r] + bias[sec] + (trow == 0 ? h0a[sec] : 0.f);
            u64 pk = (u64)f2bf(e[0]) | ((u64)f2bf(e[1]) << 16)
                   | ((u64)f2bf(e[2]) << 32) | ((u64)f2bf(e[3]) << 48);
            *(u64*)(xw + ((size_t)trow * BBATCH + bb) * G4 + (size_t)n * 4) = pk;
          }
        }
      }
      __syncthreads();           // all waves' stores drained (vmcnt) before publish
      if (tid == 0) {
        __builtin_amdgcn_fence(__ATOMIC_RELEASE, "agent");   // wbl2 only, no inv
        __hip_atomic_fetch_add(&cnt[c], 1, __ATOMIC_RELAXED, __HIP_MEMORY_SCOPE_AGENT);
      }
    }
    return;
  }

  // ================= scan branch (blocks 0..63) =================
  int lr = lane & 15, q = lane >> 4;
  int b0 = blockIdx.x * 4;
  signed char* hqb = (signed char*)lds;   // 8KB dbuf int8 h A-frags
  int nn = wv * 16 + lr;

  i32x4 wf[4][4];
  {
    const i32x4* wp = (const i32x4*)wq;
#pragma unroll
    for (int sec = 0; sec < 4; ++sec)
#pragma unroll
      for (int kt = 0; kt < 4; ++kt) wf[sec][kt] = wp[((wv * 4 + sec) * 4 + kt) * 64 + lane];
  }
  float dr[4];
#pragma unroll
  for (int sec = 0; sec < 4; ++sec) dr[sec] = dsc[sec * 256 + nn];
  float cr = c0[nn], lh = 0.f;

  *(u64*)(hqb + tid * 8) = 0ull;   // zero both hq buffers

  // gate chunk 0: relaxed poll, single acquire fence
  if (tid == 0) {
    while (__hip_atomic_load(&cnt[0], __ATOMIC_RELAXED, __HIP_MEMORY_SCOPE_AGENT) < 256)
      __builtin_amdgcn_s_sleep(32);
    __builtin_amdgcn_fence(__ATOMIC_ACQUIRE, "agent");   // one inv per gate
  }
  __syncthreads();   // hq zero + gate visible

  unsigned short* ldb = xw + (size_t)(b0 + q) * G4 + (size_t)nn * 4;
  unsigned short* stb = xw + (size_t)(b0 + q) * G4 + nn;
  u64 xq[4];
#pragma unroll
  for (int s = 0; s < 2; ++s) {
    xq[s] = *(const u64*)ldb;
    ldb += (size_t)BBATCH * G4;
  }

  const int hqr = lane * 16;
  const int hqw = (wv >> 2) * 1024 + (wv & 3) * 256 + q * 64 + lr;
  const i32x4 zero4 = {0, 0, 0, 0};
  int gated = 0;

#define STEP(XC, XL, RB) { \
    XL = *(const u64*)ldb; \
    ldb += (size_t)BBATCH * G4; \
    i32x4 acc[4]; \
    __builtin_amdgcn_s_setprio(1); \
    _Pragma("unroll") \
    for (int kt = 0; kt < 4; ++kt) { \
      i32x4 af = *(const i32x4*)(hqb + (RB) + hqr + kt * 1024); \
      _Pragma("unroll") \
      for (int sec = 0; sec < 4; ++sec) \
        acc[sec] = __builtin_amdgcn_mfma_i32_16x16x64_i8(af, wf[sec][kt], kt == 0 ? zero4 : acc[sec], 0, 0, 0); \
    } \
    __builtin_amdgcn_s_setprio(0); \
    { \
      u64 v = XC; \
      float gi = fmaf(dr[0], (float)acc[0][0], bf2f((unsigned int)(v & 0xffffu))); \
      float gf = fmaf(dr[1], (float)acc[1][0], bf2f((unsigned int)((v >> 16) & 0xffffu))); \
      float gj = fmaf(dr[2], (float)acc[2][0], bf2f((unsigned int)((v >> 32) & 0xffffu))); \
      float go = fmaf(dr[3], (float)acc[3][0], bf2f((unsigned int)(v >> 48))); \
      float iv = __builtin_amdgcn_rcpf(1.f + __expf(-gi)); \
      float fv = __builtin_amdgcn_rcpf(1.f + __expf(-gf)); \
      float ov = __builtin_amdgcn_rcpf(1.f + __expf(-go)); \
      float jv = fmaf(-2.f, __builtin_amdgcn_rcpf(1.f + __expf(2.f * gj)), 1.f); \
      float cn = fmaf(fv, cr, iv * jv); \
      cr = cn; \
      float th = fmaf(-2.f, __builtin_amdgcn_rcpf(1.f + __expf(2.f * cn)), 1.f); \
      float hn = ov * th; \
      lh = hn; \
      hqb[((RB) ^ 4096) + hqw] = (signed char)(int)rintf(hn * 127.f); \
      stb[0] = f2bf(hn); \
    } \
    stb += (size_t)BBATCH * G4; \
    asm volatile("s_waitcnt lgkmcnt(0)" ::: "memory"); \
    __builtin_amdgcn_s_barrier(); \
  }

#pragma unroll 1
  for (int t = 0; t < TT; t += 4) {
    int need = (t + 5) >> 6;
    need = need > 15 ? 15 : need;
    if (need > gated) {
      if (tid == 0) {
        while (__hip_atomic_load(&cnt[need], __ATOMIC_RELAXED, __HIP_MEMORY_SCOPE_AGENT) < 256)
          __builtin_amdgcn_s_sleep(32);
        __builtin_amdgcn_fence(__ATOMIC_ACQUIRE, "agent");   // one inv per gate
      }
      __syncthreads();
      gated = need;
    }
    STEP(xq[0], xq[2], 0)
    STEP(xq[1], xq[3], 4096)
    STEP(xq[2], xq[0], 0)
    STEP(xq[3], xq[1], 4096)
  }
#undef STEP

  const size_t youts = (size_t)BBATCH * TT * DD;
  out[youts + (size_t)(b0 + q) * HH + nn] = lh;
  out[youts + (size_t)BBATCH * HH + (size_t)(b0 + q) * HH + nn] = cr;
}

// ---------------- phase 3: y = hs @ W_y + b_y ----------------
__global__ __launch_bounds__(256, 4) void y_gemm(const unsigned short* __restrict__ hsx,
                                                 const unsigned short* __restrict__ wyt,
                                                 const float* __restrict__ by,
                                                 float* __restrict__ y) {
  __shared__ __align__(16) unsigned short ha[64 * 256];  // 32KB
  int tid = threadIdx.x;
  int mt = blockIdx.x;
  int bb = mt >> 4;
  int t0 = (mt & 15) * 64;
  {
    int row = tid >> 2, q = tid & 3;
    const unsigned short* src = hsx + (size_t)(t0 + row) * (size_t)(BBATCH * 1024) + (size_t)bb * 1024;
#pragma unroll
    for (int i = 0; i < 8; ++i) {
      int u = q + i * 4;
      int4 vv = *(const int4*)(src + u * 8);
      *(int4*)((char*)ha + row * 512 + ((u * 16) ^ ((row & 7) << 4))) = vv;
    }
  }
  __syncthreads();
  int lane = tid & 63, wv = tid >> 6;
  int wr = wv >> 1, wc = wv & 1;
  int lr = lane & 15, hi = lane >> 4;
#pragma unroll 1
  for (int dblk = 0; dblk < 2; ++dblk) {
    f32x4 acc[2][4];
#pragma unroll
    for (int a = 0; a < 2; ++a)
#pragma unroll
      for (int b = 0; b < 4; ++b) acc[a][b] = (f32x4){0.f, 0.f, 0.f, 0.f};
    int dbase = dblk * 128 + wc * 64;
#pragma unroll
    for (int k0 = 0; k0 < 8; ++k0) {
      bf16x8 a[2], b[4];
#pragma unroll
      for (int mti = 0; mti < 2; ++mti) {
        int row = wr * 32 + mti * 16 + lr;
        a[mti] = *(const bf16x8*)((const char*)ha + row * 512 + ((k0 * 64 + hi * 16) ^ ((row & 7) << 4)));
      }
#pragma unroll
      for (int nt = 0; nt < 4; ++nt) {
        b[nt] = *(const bf16x8*)(wyt + (size_t)(dbase + nt * 16 + lr) * 256 + k0 * 32 + hi * 8);
#pragma unroll
        for (int mti = 0; mti < 2; ++mti)
          acc[mti][nt] = __builtin_amdgcn_mfma_f32_16x16x32_bf16(a[mti], b[nt], acc[mti][nt], 0, 0, 0);
      }
    }
#pragma unroll
    for (int mti = 0; mti < 2; ++mti)
#pragma unroll
      for (int nt = 0; nt < 4; ++nt) {
        int d = dbase + nt * 16 + lr;
        float bv = by[d];
#pragma unroll
        for (int r = 0; r < 4; ++r) {
          int trow = t0 + wr * 32 + mti * 16 + hi * 4 + r;
          y[((size_t)bb * TT + trow) * DD + d] = acc[mti][nt][r] + bv;
        }
      }
  }
}

// ---------------- launch ----------------
extern "C" void kernel_launch(void* const* d_in, const int* in_sizes, int n_in,
                              void* d_out, int out_size, void* d_ws, size_t ws_size,
                              hipStream_t stream) {
  const float* x   = (const float*)d_in[0];
  const float* wih = (const float*)d_in[1];
  const float* bih = (const float*)d_in[2];
  const float* whh = (const float*)d_in[3];
  const float* h0  = (const float*)d_in[4];
  const float* c0  = (const float*)d_in[5];
  const float* wy  = (const float*)d_in[6];
  const float* by  = (const float*)d_in[7];
  float* out = (float*)d_out;
  char* ws = (char*)d_ws;

  size_t off = 0;
  unsigned short* xw = (unsigned short*)(ws + off);
  off += (size_t)(TT + 2) * BBATCH * G4 * 2;   // 512MB + 2-row prefetch slack
  unsigned short* wbf = (unsigned short*)(ws + off); off += (size_t)G4 * DD * 2;
  unsigned short* wyt = (unsigned short*)(ws + off); off += (size_t)HH * DD * 2;
  signed char* wq = (signed char*)(ws + off); off += (size_t)G4 * HH;
  float* dsc = (float*)(ws + off); off += G4 * 4;
  float* hh0 = (float*)(ws + off); off += G4 * 4;
  int* cnt = (int*)(ws + off); off += 64;

  hipLaunchKernelGGL(prep_wih, dim3(1024), dim3(64), 0, stream, wih, wbf);
  hipLaunchKernelGGL(prep_wyt, dim3(256), dim3(256), 0, stream, wy, wyt);
  hipLaunchKernelGGL(prep_whh, dim3(1024), dim3(64), 0, stream, whh, h0, wq, dsc, hh0);
  hipLaunchKernelGGL(zero_sync, dim3(1), dim3(64), 0, stream, cnt);
  hipLaunchKernelGGL(fused_scan, dim3(256), dim3(1024), 0, stream,
                     x, wbf, bih, hh0, xw, wq, dsc, c0, out, cnt);
  hipLaunchKernelGGL(y_gemm, dim3(4096), dim3(256), 0, stream, xw, wyt, by, out);
}

// Round 10
// 1462.181 us; speedup vs baseline: 1.3077x; 1.1374x over previous
//
#include <hip/hip_runtime.h>
#include <hip/hip_bf16.h>
#include <stdint.h>

#define TT 1024
#define BBATCH 256
#define DD 256
#define HH 256
#define G4 1024   // 4*H

typedef float f32x4 __attribute__((ext_vector_type(4)));
typedef short bf16x8 __attribute__((ext_vector_type(8)));
typedef int   i32x4  __attribute__((ext_vector_type(4)));
typedef unsigned long long u64;

__device__ __forceinline__ float bf2f(unsigned int u) {
  union { unsigned int i; float f; } v; v.i = u << 16; return v.f;
}
__device__ __forceinline__ unsigned short f2bf(float f) {
  union { float f; unsigned int i; } v; v.f = f;
  unsigned int r = v.i + 0x7FFFu + ((v.i >> 16) & 1u);
  return (unsigned short)(r >> 16);
}
__device__ __forceinline__ bf16x8 pack8(const float4& u, const float4& v) {
  bf16x8 r;
  r[0] = (short)f2bf(u.x); r[1] = (short)f2bf(u.y); r[2] = (short)f2bf(u.z); r[3] = (short)f2bf(u.w);
  r[4] = (short)f2bf(v.x); r[5] = (short)f2bf(v.y); r[6] = (short)f2bf(v.z); r[7] = (short)f2bf(v.w);
  return r;
}
// cross-XCD payload access: agent-scope relaxed => sc1 write-through / read-through
// (bypasses the non-coherent per-XCD L2; completes at the coherent point). NO fences.
__device__ __forceinline__ void xstore(u64* p, u64 v) {
  __hip_atomic_store(p, v, __ATOMIC_RELAXED, __HIP_MEMORY_SCOPE_AGENT);
}
__device__ __forceinline__ u64 xload(const u64* p) {
  return __hip_atomic_load(p, __ATOMIC_RELAXED, __HIP_MEMORY_SCOPE_AGENT);
}

// ---------------- prep kernels ----------------

// W_ih fp32 [1024 g][256 k] -> bf16 frag-packed for the worker's B staging.
__global__ void prep_wih(const float* __restrict__ wih, unsigned short* __restrict__ out) {
  int g = blockIdx.x;          // 0..1023
  int lane = threadIdx.x;      // 0..63
  int sec = g >> 8, n = g & 255;
  int wc = n >> 5, nt = (n >> 4) & 1, lr = n & 15;
  int k0 = lane * 4;
  int s = k0 >> 5, hi = (k0 >> 3) & 3, el = k0 & 7;
  size_t us = (size_t)s * 32768
            + (size_t)((wc * 8 + sec * 2 + nt) * 64 + (lr | (hi << 4))) * 8 + el;
#pragma unroll
  for (int j2 = 0; j2 < 4; ++j2) out[us + j2] = f2bf(wih[g * 256 + k0 + j2]);
}

__global__ void prep_wyt(const float* __restrict__ wy, unsigned short* __restrict__ wyt) {
  int k = blockIdx.x;
  int d = threadIdx.x;
  wyt[d * 256 + k] = f2bf(wy[k * 256 + d]);
}

// W_hh fp32 [1024 g][256 k] -> per-row-scaled int8 packed in MFMA B-frag order for the
// 16-wave scan: g = sec*256 + n, n = w*16 + cl. Frag slot [((w*4+sec)*4+kt)*64 + lane].
__global__ void prep_whh(const float* __restrict__ whh, const float* __restrict__ h0,
                         signed char* __restrict__ wq, float* __restrict__ dsc,
                         float* __restrict__ hh0) {
  int g = blockIdx.x;
  int lane = threadIdx.x;
  float v[4];
  float mx = 0.f, acc = 0.f;
#pragma unroll
  for (int j = 0; j < 4; ++j) {
    v[j] = whh[g * 256 + lane * 4 + j];
    mx = fmaxf(mx, fabsf(v[j]));
    acc += v[j] * h0[lane * 4 + j];
  }
#pragma unroll
  for (int off = 32; off; off >>= 1) {
    mx  = fmaxf(mx, __shfl_xor(mx, off));
    acc = acc + __shfl_xor(acc, off);
  }
  mx = fmaxf(mx, 1e-12f);
  if (lane == 0) { dsc[g] = mx / (127.f * 127.f); hh0[g] = acc; }
  int sec = g >> 8, w = (g >> 4) & 15, cl = g & 15;
  float inv = 127.f / mx;
  int k0 = lane * 4;
  int kt = k0 >> 6, hi = (k0 >> 4) & 3, jj = k0 & 15;
  int base = (((w * 4 + sec) * 4 + kt) * 64 + (cl | (hi << 4))) * 16 + jj;
#pragma unroll
  for (int j = 0; j < 4; ++j) {
    int q = (int)rintf(v[j] * inv);
    q = q > 127 ? 127 : (q < -127 ? -127 : q);
    wq[base + j] = (signed char)q;
  }
}

__global__ void zero_sync(int* __restrict__ cnt) {
  if (threadIdx.x < 16) cnt[threadIdx.x] = 0;
}

// ---------------- fused: 64 scan blocks + 192 xw-producer blocks ----------------
// grid 256 x 1024 thr, 1 block/CU, all co-resident. Workers produce xw in 64-step
// chunks; scan gates prefetches on cnt[c]==256. Cross-XCD protocol: sc1 (write-/read-
// through) accesses on xw only; flags relaxed agent atomics; NO cache-maintenance fences.
__global__ __launch_bounds__(1024, 4) void fused_scan(
    const float* __restrict__ x, const unsigned short* __restrict__ wb,
    const float* __restrict__ bih, const float* __restrict__ hh0,
    unsigned short* xw, const signed char* __restrict__ wq,
    const float* __restrict__ dsc, const float* __restrict__ c0,
    float* __restrict__ out, int* cnt) {
  __shared__ __align__(16) char lds[131072];
  int tid = threadIdx.x;
  int lane = tid & 63, wv = tid >> 6;

  if (blockIdx.x >= 64) {
    // ================= worker branch: xw tiles (64 trow x 1024 g) =================
    int wid = blockIdx.x - 64;   // 0..191
    int wr = wv >> 3, wc = wv & 7;
    int lr = lane & 15, hi = lane >> 4;
#pragma unroll 1
    for (int tile = wid; tile < 4096; tile += 192) {
      int c = tile >> 8, bb = tile & 255;
      int t0 = c * 64;
      const float* xb = x + ((size_t)bb * TT + t0) * DD;
      f32x4 acc[2][8];   // [mti][sec*2+nt]
#pragma unroll
      for (int m = 0; m < 2; ++m)
#pragma unroll
        for (int j = 0; j < 8; ++j) acc[m][j] = (f32x4){0.f, 0.f, 0.f, 0.f};
      int4 b4[4];
      float4 a4[4];
      bf16x8 afr[2];
      // prologue: slice 0
#pragma unroll
      for (int i = 0; i < 4; ++i)
        b4[i] = *(const int4*)(wb + i * 8192 + tid * 8);
#pragma unroll
      for (int m = 0; m < 2; ++m) {
        const float* ap = xb + (size_t)(wr * 32 + m * 16 + lr) * DD + hi * 8;
        a4[m * 2] = *(const float4*)ap;
        a4[m * 2 + 1] = *(const float4*)(ap + 4);
      }
#pragma unroll
      for (int i = 0; i < 4; ++i)
        *(int4*)(lds + i * 16384 + tid * 16) = b4[i];
      afr[0] = pack8(a4[0], a4[1]);
      afr[1] = pack8(a4[2], a4[3]);
      __syncthreads();
#pragma unroll 1
      for (int s = 0; s < 8; ++s) {
        char* bufc = lds + (s & 1) * 65536;
        if (s < 7) {
#pragma unroll
          for (int i = 0; i < 4; ++i)
            b4[i] = *(const int4*)(wb + (s + 1) * 32768 + i * 8192 + tid * 8);
#pragma unroll
          for (int m = 0; m < 2; ++m) {
            const float* ap = xb + (size_t)(wr * 32 + m * 16 + lr) * DD + (s + 1) * 32 + hi * 8;
            a4[m * 2] = *(const float4*)ap;
            a4[m * 2 + 1] = *(const float4*)(ap + 4);
          }
        }
#pragma unroll
        for (int j = 0; j < 8; ++j) {
          bf16x8 bf = *(const bf16x8*)(bufc + ((wc * 8 + j) * 64 + lane) * 16);
          acc[0][j] = __builtin_amdgcn_mfma_f32_16x16x32_bf16(afr[0], bf, acc[0][j], 0, 0, 0);
          acc[1][j] = __builtin_amdgcn_mfma_f32_16x16x32_bf16(afr[1], bf, acc[1][j], 0, 0, 0);
        }
        if (s < 7) {
          afr[0] = pack8(a4[0], a4[1]);
          afr[1] = pack8(a4[2], a4[3]);
          char* bufn = lds + ((s + 1) & 1) * 65536;
#pragma unroll
          for (int i = 0; i < 4; ++i)
            *(int4*)(bufn + i * 16384 + tid * 16) = b4[i];
        }
        __syncthreads();
      }
      // epilogue: pack 4 secs -> u64 (+bias, +hh0 at trow 0), sc1 write-through stores
#pragma unroll
      for (int nt = 0; nt < 2; ++nt) {
        int n = wc * 32 + nt * 16 + lr;
        float bias[4], h0a[4];
#pragma unroll
        for (int sec = 0; sec < 4; ++sec) { bias[sec] = bih[sec * 256 + n]; h0a[sec] = hh0[sec * 256 + n]; }
#pragma unroll
        for (int m = 0; m < 2; ++m) {
#pragma unroll
          for (int r = 0; r < 4; ++r) {
            int trow = t0 + wr * 32 + m * 16 + hi * 4 + r;
            float e[4];
#pragma unroll
            for (int sec = 0; sec < 4; ++sec)
              e[sec] = acc[m][sec * 2 + nt][r] + bias[sec] + (trow == 0 ? h0a[sec] : 0.f);
            u64 pk = (u64)f2bf(e[0]) | ((u64)f2bf(e[1]) << 16)
                   | ((u64)f2bf(e[2]) << 32) | ((u64)f2bf(e[3]) << 48);
            xstore((u64*)(xw + ((size_t)trow * BBATCH + bb) * G4 + (size_t)n * 4), pk);
          }
        }
      }
      // __syncthreads: each wave passes only after its own vmcnt(0) -> all sc1 stores
      // have completed at the coherent point. Then publish with a relaxed flag add.
      __syncthreads();
      if (tid == 0)
        __hip_atomic_fetch_add(&cnt[c], 1, __ATOMIC_RELAXED, __HIP_MEMORY_SCOPE_AGENT);
    }
    return;
  }

  // ================= scan branch (blocks 0..63) =================
  int lr = lane & 15, q = lane >> 4;
  int b0 = blockIdx.x * 4;
  signed char* hqb = (signed char*)lds;   // 8KB dbuf int8 h A-frags
  int nn = wv * 16 + lr;

  i32x4 wf[4][4];
  {
    const i32x4* wp = (const i32x4*)wq;
#pragma unroll
    for (int sec = 0; sec < 4; ++sec)
#pragma unroll
      for (int kt = 0; kt < 4; ++kt) wf[sec][kt] = wp[((wv * 4 + sec) * 4 + kt) * 64 + lane];
  }
  float dr[4];
#pragma unroll
  for (int sec = 0; sec < 4; ++sec) dr[sec] = dsc[sec * 256 + nn];
  float cr = c0[nn], lh = 0.f;

  *(u64*)(hqb + tid * 8) = 0ull;   // zero both hq buffers

  // gate chunk 0: relaxed poll only (sc1 reads don't need an invalidate)
  if (tid == 0) {
    while (__hip_atomic_load(&cnt[0], __ATOMIC_RELAXED, __HIP_MEMORY_SCOPE_AGENT) < 256)
      __builtin_amdgcn_s_sleep(32);
  }
  __syncthreads();   // hq zero + gate visible

  unsigned short* ldb = xw + (size_t)(b0 + q) * G4 + (size_t)nn * 4;
  unsigned short* stb = xw + (size_t)(b0 + q) * G4 + nn;
  u64 xq[4];
#pragma unroll
  for (int s = 0; s < 2; ++s) {
    xq[s] = xload((const u64*)ldb);
    ldb += (size_t)BBATCH * G4;
  }

  const int hqr = lane * 16;
  const int hqw = (wv >> 2) * 1024 + (wv & 3) * 256 + q * 64 + lr;
  const i32x4 zero4 = {0, 0, 0, 0};
  int gated = 0;

#define STEP(XC, XL, RB) { \
    XL = xload((const u64*)ldb); \
    ldb += (size_t)BBATCH * G4; \
    i32x4 acc[4]; \
    __builtin_amdgcn_s_setprio(1); \
    _Pragma("unroll") \
    for (int kt = 0; kt < 4; ++kt) { \
      i32x4 af = *(const i32x4*)(hqb + (RB) + hqr + kt * 1024); \
      _Pragma("unroll") \
      for (int sec = 0; sec < 4; ++sec) \
        acc[sec] = __builtin_amdgcn_mfma_i32_16x16x64_i8(af, wf[sec][kt], kt == 0 ? zero4 : acc[sec], 0, 0, 0); \
    } \
    __builtin_amdgcn_s_setprio(0); \
    { \
      u64 v = XC; \
      float gi = fmaf(dr[0], (float)acc[0][0], bf2f((unsigned int)(v & 0xffffu))); \
      float gf = fmaf(dr[1], (float)acc[1][0], bf2f((unsigned int)((v >> 16) & 0xffffu))); \
      float gj = fmaf(dr[2], (float)acc[2][0], bf2f((unsigned int)((v >> 32) & 0xffffu))); \
      float go = fmaf(dr[3], (float)acc[3][0], bf2f((unsigned int)(v >> 48))); \
      float iv = __builtin_amdgcn_rcpf(1.f + __expf(-gi)); \
      float fv = __builtin_amdgcn_rcpf(1.f + __expf(-gf)); \
      float ov = __builtin_amdgcn_rcpf(1.f + __expf(-go)); \
      float jv = fmaf(-2.f, __builtin_amdgcn_rcpf(1.f + __expf(2.f * gj)), 1.f); \
      float cn = fmaf(fv, cr, iv * jv); \
      cr = cn; \
      float th = fmaf(-2.f, __builtin_amdgcn_rcpf(1.f + __expf(2.f * cn)), 1.f); \
      float hn = ov * th; \
      lh = hn; \
      hqb[((RB) ^ 4096) + hqw] = (signed char)(int)rintf(hn * 127.f); \
      stb[0] = f2bf(hn); \
    } \
    stb += (size_t)BBATCH * G4; \
    asm volatile("s_waitcnt lgkmcnt(0)" ::: "memory"); \
    __builtin_amdgcn_s_barrier(); \
  }

#pragma unroll 1
  for (int t = 0; t < TT; t += 4) {
    int need = (t + 5) >> 6;
    need = need > 15 ? 15 : need;
    if (need > gated) {
      if (tid == 0) {
        while (__hip_atomic_load(&cnt[need], __ATOMIC_RELAXED, __HIP_MEMORY_SCOPE_AGENT) < 256)
          __builtin_amdgcn_s_sleep(32);
      }
      __syncthreads();
      gated = need;
    }
    STEP(xq[0], xq[2], 0)
    STEP(xq[1], xq[3], 4096)
    STEP(xq[2], xq[0], 0)
    STEP(xq[3], xq[1], 4096)
  }
#undef STEP

  const size_t youts = (size_t)BBATCH * TT * DD;
  out[youts + (size_t)(b0 + q) * HH + nn] = lh;
  out[youts + (size_t)BBATCH * HH + (size_t)(b0 + q) * HH + nn] = cr;
}

// ---------------- phase 3: y = hs @ W_y + b_y ----------------
__global__ __launch_bounds__(256, 4) void y_gemm(const unsigned short* __restrict__ hsx,
                                                 const unsigned short* __restrict__ wyt,
                                                 const float* __restrict__ by,
                                                 float* __restrict__ y) {
  __shared__ __align__(16) unsigned short ha[64 * 256];  // 32KB
  int tid = threadIdx.x;
  int mt = blockIdx.x;
  int bb = mt >> 4;
  int t0 = (mt & 15) * 64;
  {
    int row = tid >> 2, q = tid & 3;
    const unsigned short* src = hsx + (size_t)(t0 + row) * (size_t)(BBATCH * 1024) + (size_t)bb * 1024;
#pragma unroll
    for (int i = 0; i < 8; ++i) {
      int u = q + i * 4;
      int4 vv = *(const int4*)(src + u * 8);
      *(int4*)((char*)ha + row * 512 + ((u * 16) ^ ((row & 7) << 4))) = vv;
    }
  }
  __syncthreads();
  int lane = tid & 63, wv = tid >> 6;
  int wr = wv >> 1, wc = wv & 1;
  int lr = lane & 15, hi = lane >> 4;
#pragma unroll 1
  for (int dblk = 0; dblk < 2; ++dblk) {
    f32x4 acc[2][4];
#pragma unroll
    for (int a = 0; a < 2; ++a)
#pragma unroll
      for (int b = 0; b < 4; ++b) acc[a][b] = (f32x4){0.f, 0.f, 0.f, 0.f};
    int dbase = dblk * 128 + wc * 64;
#pragma unroll
    for (int k0 = 0; k0 < 8; ++k0) {
      bf16x8 a[2], b[4];
#pragma unroll
      for (int mti = 0; mti < 2; ++mti) {
        int row = wr * 32 + mti * 16 + lr;
        a[mti] = *(const bf16x8*)((const char*)ha + row * 512 + ((k0 * 64 + hi * 16) ^ ((row & 7) << 4)));
      }
#pragma unroll
      for (int nt = 0; nt < 4; ++nt) {
        b[nt] = *(const bf16x8*)(wyt + (size_t)(dbase + nt * 16 + lr) * 256 + k0 * 32 + hi * 8);
#pragma unroll
        for (int mti = 0; mti < 2; ++mti)
          acc[mti][nt] = __builtin_amdgcn_mfma_f32_16x16x32_bf16(a[mti], b[nt], acc[mti][nt], 0, 0, 0);
      }
    }
#pragma unroll
    for (int mti = 0; mti < 2; ++mti)
#pragma unroll
      for (int nt = 0; nt < 4; ++nt) {
        int d = dbase + nt * 16 + lr;
        float bv = by[d];
#pragma unroll
        for (int r = 0; r < 4; ++r) {
          int trow = t0 + wr * 32 + mti * 16 + hi * 4 + r;
          y[((size_t)bb * TT + trow) * DD + d] = acc[mti][nt][r] + bv;
        }
      }
  }
}

// ---------------- launch ----------------
extern "C" void kernel_launch(void* const* d_in, const int* in_sizes, int n_in,
                              void* d_out, int out_size, void* d_ws, size_t ws_size,
                              hipStream_t stream) {
  const float* x   = (const float*)d_in[0];
  const float* wih = (const float*)d_in[1];
  const float* bih = (const float*)d_in[2];
  const float* whh = (const float*)d_in[3];
  const float* h0  = (const float*)d_in[4];
  const float* c0  = (const float*)d_in[5];
  const float* wy  = (const float*)d_in[6];
  const float* by  = (const float*)d_in[7];
  float* out = (float*)d_out;
  char* ws = (char*)d_ws;

  size_t off = 0;
  unsigned short* xw = (unsigned short*)(ws + off);
  off += (size_t)(TT + 2) * BBATCH * G4 * 2;   // 512MB + 2-row prefetch slack
  unsigned short* wbf = (unsigned short*)(ws + off); off += (size_t)G4 * DD * 2;
  unsigned short* wyt = (unsigned short*)(ws + off); off += (size_t)HH * DD * 2;
  signed char* wq = (signed char*)(ws + off); off += (size_t)G4 * HH;
  float* dsc = (float*)(ws + off); off += G4 * 4;
  float* hh0 = (float*)(ws + off); off += G4 * 4;
  int* cnt = (int*)(ws + off); off += 64;

  hipLaunchKernelGGL(prep_wih, dim3(1024), dim3(64), 0, stream, wih, wbf);
  hipLaunchKernelGGL(prep_wyt, dim3(256), dim3(256), 0, stream, wy, wyt);
  hipLaunchKernelGGL(prep_whh, dim3(1024), dim3(64), 0, stream, whh, h0, wq, dsc, hh0);
  hipLaunchKernelGGL(zero_sync, dim3(1), dim3(64), 0, stream, cnt);
  hipLaunchKernelGGL(fused_scan, dim3(256), dim3(1024), 0, stream,
                     x, wbf, bih, hh0, xw, wq, dsc, c0, out, cnt);
  hipLaunchKernelGGL(y_gemm, dim3(4096), dim3(256), 0, stream, xw, wyt, by, out);
}